// Round 11
// baseline (158.222 us; speedup 1.0000x reference)
//
#include <hip/hip_runtime.h>
#include <math.h>

// Problem constants (B=4, S=2048, E=1024, A=64)
#define BATCH 4
#define SLEN  2048
#define EMB   1024
#define AH    64

typedef __attribute__((ext_vector_type(8))) short bf16x8;
typedef __attribute__((ext_vector_type(4))) float f32x4;

#define MFMA16(a, b, c) __builtin_amdgcn_mfma_f32_16x16x32_bf16((a), (b), (c), 0, 0, 0)

// async 16B global->LDS: zero VGPR cost, guaranteed in-flight batching.
__device__ __forceinline__ void async16(const void* g, void* l) {
  __builtin_amdgcn_global_load_lds(
      (const __attribute__((address_space(1))) unsigned int*)g,
      (__attribute__((address_space(3))) unsigned int*)l, 16, 0, 0);
}

__device__ __forceinline__ short f2bf(float x) {  // RNE
  union { float f; unsigned u; } v; v.f = x;
  unsigned r = v.u + 0x7fffu + ((v.u >> 16) & 1u);
  return (short)(r >> 16);
}
__device__ __forceinline__ float bf2f(short h) {
  union { unsigned u; float f; } v; v.u = ((unsigned)(unsigned short)h) << 16;
  return v.f;
}

// Truncate-split 8 fp32 -> bf16 hi (high16) + bf16 lo (trunc of residual).
__device__ __forceinline__ void split_trunc(float4 a0, float4 a1, bf16x8& hi, bf16x8& lo) {
  unsigned c[8] = {__float_as_uint(a0.x), __float_as_uint(a0.y), __float_as_uint(a0.z),
                   __float_as_uint(a0.w), __float_as_uint(a1.x), __float_as_uint(a1.y),
                   __float_as_uint(a1.z), __float_as_uint(a1.w)};
  union { bf16x8 v; unsigned d[4]; } H, L;
  H.d[0] = __builtin_amdgcn_perm(c[1], c[0], 0x07060302u);
  H.d[1] = __builtin_amdgcn_perm(c[3], c[2], 0x07060302u);
  H.d[2] = __builtin_amdgcn_perm(c[5], c[4], 0x07060302u);
  H.d[3] = __builtin_amdgcn_perm(c[7], c[6], 0x07060302u);
  unsigned e[8];
#pragma unroll
  for (int j = 0; j < 8; ++j)
    e[j] = __float_as_uint(__uint_as_float(c[j]) - __uint_as_float(c[j] & 0xffff0000u));
  L.d[0] = __builtin_amdgcn_perm(e[1], e[0], 0x07060302u);
  L.d[1] = __builtin_amdgcn_perm(e[3], e[2], 0x07060302u);
  L.d[2] = __builtin_amdgcn_perm(e[5], e[4], 0x07060302u);
  L.d[3] = __builtin_amdgcn_perm(e[7], e[6], 0x07060302u);
  hi = H.v; lo = L.v;
}

// Triangular chunk-slot offset: off(qt) = sum_{q<qt} (q/2 + 1)
__device__ __forceinline__ int slot_off(int qt) {
  return (qt == 0) ? 0 : qt + (((qt - 1) * (qt - 1)) >> 2);
}

// Kpack chunk layout (shorts), per (b, chunk of 128 keys), 24576 shorts = 48 KB:
//   [0,8192):      KBhi  [kb(8)][a32(2)][lane(64)][8]   S-MFMA B-frag, hi plane
//   [8192,16384):  KBlo  same, lo plane
//   [16384,24576): VB    [kc2(4)][nt(4)][lane(64)][8] PV-MFMA B-frag (hi only)
#define CH_SHORTS 24576

// Per-(b,qt) completion counters: flags[i*16], i = b*32+qt (128 counters).
#define CNT(i) flags[(size_t)(i) << 4]

// ---------------------------------------------------------------------------
// 3-dispatch pipeline. R10 ledger: phase-internal variants all within +-2us
// noise; remaining lever is DISPATCH COUNT. This round: merge folded into
// flash via last-block-merges (R3/R6-validated release/fenceless protocol;
// no spins). Merges for early qt ride flash's tail where CUs idle.
// ---------------------------------------------------------------------------

// ---------------------------------------------------------------------------
// Kernel 0: pack Wk -> BpkG; block 0 also zeroes the 128 qt-counters.
// ---------------------------------------------------------------------------
__global__ __launch_bounds__(256) void prep_wk_kernel(const float* __restrict__ Wk,
                                                      short* __restrict__ BpkG,
                                                      int* __restrict__ flags) {
  if (blockIdx.x == 0 && threadIdx.x < 128) CNT(threadIdx.x) = 0;
  int tg = blockIdx.x * 256 + threadIdx.x;  // 8192 = 32kc * 4nt * 64lane
  int kc = tg >> 8, rem = tg & 255, nt = rem >> 6, lane = rem & 63;
  int n = nt * 16 + (lane & 15);
  int k = kc * 32 + (lane >> 4) * 8;
  const float* src = Wk + (size_t)n * EMB + k;
  float4 a0 = *(const float4*)src;
  float4 a1 = *(const float4*)(src + 4);
  bf16x8 hi, lo;
  split_trunc(a0, a1, hi, lo);
  short* dst = BpkG + ((size_t)(kc * 4 + nt) * 128 + lane) * 8;  // pl=0
  *(bf16x8*)dst = hi;
  *(bf16x8*)(dst + 512) = lo;  // pl=1
}

// ---------------------------------------------------------------------------
// Kernel 1 (R7-validated): K = emb @ Wk^T, ONE-BARRIER, BpkG-fed.
// ---------------------------------------------------------------------------
__global__ __launch_bounds__(256) void gemm_k_kernel(const float* __restrict__ emb,
                                                     const short* __restrict__ BpkG,
                                                     short* __restrict__ Kpack) {
  __shared__ __align__(16) float eT[16384];  // 64 KB: [s(16)][row(16)][64f swizzled]

  const int t = threadIdx.x;
  const int w = t >> 6, l = t & 63, lm = l & 15, quad = l >> 4;
  const int nt = w;
  const int row0 = blockIdx.x * 16;

  {  // stage: row rowl, swizzled du slot; dest = wave base + lane*16 (linear)
    int rowl = 4 * w + (l >> 4);
    int du = (l & 15) ^ (rowl & 7);
    const float* src = emb + (size_t)(row0 + rowl) * EMB + du * 4;
#pragma unroll
    for (int s = 0; s < 16; ++s)
      async16(src + s * 64, eT + s * 1024 + w * 256);
  }
  __syncthreads();  // the ONLY barrier: drains all 16 tiles

  f32x4 acc = {0.f, 0.f, 0.f, 0.f};
#pragma unroll
  for (int s = 0; s < 16; ++s) {
    const char* eS = (const char*)(eT + s * 1024);
    const short* bg = BpkG + (size_t)s * 8192;
#pragma unroll
    for (int kc = 0; kc < 2; ++kc) {
      int du0 = kc * 8 + quad * 2;
      float4 a0 = *(const float4*)(eS + lm * 256 + ((du0) ^ (lm & 7)) * 16);
      float4 a1 = *(const float4*)(eS + lm * 256 + ((du0 + 1) ^ (lm & 7)) * 16);
      bf16x8 ahi, alo;
      split_trunc(a0, a1, ahi, alo);
      bf16x8 bhi = *(const bf16x8*)(bg + (((kc * 4 + nt) * 2 + 0) * 64 + l) * 8);
      bf16x8 blo = *(const bf16x8*)(bg + (((kc * 4 + nt) * 2 + 1) * 64 + l) * 8);
      acc = MFMA16(ahi, bhi, acc);
      acc = MFMA16(ahi, blo, acc);
      acc = MFMA16(alo, bhi, acc);
    }
  }

  // epilogue: C layout (row=quad*4+r, col a=nt*16+lm) -> Kpack fragment scatter
  const int a = nt * 16 + lm;
#pragma unroll
  for (int r = 0; r < 4; ++r) {
    int srow = row0 + quad * 4 + r;
    float v = acc[r];
    short h = f2bf(v);
    short lo2 = f2bf(v - bf2f(h));
    int bb = srow >> 11, si = srow & 2047, c = si >> 7, key = si & 127;
    int kb = key >> 4, klm = key & 15;
    size_t cb = (size_t)(bb * 16 + c) * CH_SHORTS;
    size_t kbo = (size_t)((kb * 2 + (a >> 5)) * 64 + ((a & 31) >> 3) * 16 + klm) * 8 + (a & 7);
    Kpack[cb + kbo] = h;
    Kpack[cb + 8192 + kbo] = lo2;
    size_t vbo = (size_t)(((key >> 5) * 4 + (a >> 4)) * 64 + ((key & 31) >> 3) * 16 + (a & 15)) * 8 + (key & 7);
    Kpack[cb + 16384 + vbo] = h;
  }
}

// ---------------------------------------------------------------------------
// Kernel 2: flash partials + LAST-BLOCK MERGE. grid (16,32,4); active iff
// 2c <= qt -> 1088 blocks (3/CU at 49.7 KB LDS, union of flash/merge views).
// After writing partials, each block releases a per-(b,qt) counter; the
// last block (old == nch-1) merges that qt inline (4 rowgroup passes,
// LDS reused). Fenceless consumer per R6 protocol.
// ---------------------------------------------------------------------------
union __align__(16) FMem {
  struct { short KLs[16384]; short Plds[4][16][132]; } f;  // flash (49.6 KB)
  struct { short ldsO[16384]; float wtab[16][17]; } m;     // merge (33.1 KB)
};

__global__ __launch_bounds__(256, 3) void flash_kernel(const short* __restrict__ Kpack,
                                                       short* __restrict__ OpartH,
                                                       float2* __restrict__ mlpart,
                                                       float* __restrict__ out,
                                                       int* __restrict__ flags) {
  const int c = blockIdx.x, qt = blockIdx.y, b = blockIdx.z;
  if (2 * c > qt) return;

  __shared__ FMem sm;
  __shared__ int s_last;

  const int t = threadIdx.x;
  const int w = t >> 6, l = t & 63, lm = l & 15, quad = l >> 4;
  const int k0 = c * 128;
  const int qr0 = qt * 64 + w * 16;
  const int nch = (qt >> 1) + 1;

  const short* chunkG = Kpack + (size_t)(b * 16 + c) * CH_SHORTS;
  // stage KBhi + KBlo: 32 slots x 1 KB
#pragma unroll
  for (int u = 0; u < 8; ++u) {
    int slot = w * 8 + u;
    async16(chunkG + slot * 512 + l * 8, sm.f.KLs + slot * 512);
  }

  // Q fragments direct-to-VGPR (rows live in chunk qt>>1's KB region)
  const short* qG = Kpack + (size_t)(b * 16 + (qt >> 1)) * CH_SHORTS + ((qt & 1) * 4 + w) * 1024;
  bf16x8 qh0 = *(const bf16x8*)(qG + l * 8);
  bf16x8 qh1 = *(const bf16x8*)(qG + 512 + l * 8);
  bf16x8 ql0 = *(const bf16x8*)(qG + 8192 + l * 8);
  bf16x8 ql1 = *(const bf16x8*)(qG + 8192 + 512 + l * 8);

  // all 16 V fragments direct from global (coalesced 16B/lane)
  bf16x8 vf[4][4];
#pragma unroll
  for (int kc2 = 0; kc2 < 4; ++kc2)
#pragma unroll
    for (int nt = 0; nt < 4; ++nt)
      vf[kc2][nt] = *(const bf16x8*)(chunkG + 16384 + ((kc2 * 4 + nt) * 64 + l) * 8);

  __syncthreads();  // drains staging (Q/V register loads also complete)

  // S = Q K^T: 8 key-groups x 2 a-chunks x split(hh+hl+lh)
  f32x4 sc[8];
#pragma unroll
  for (int kg = 0; kg < 8; ++kg) {
    bf16x8 bh0 = *(const bf16x8*)(sm.f.KLs + ((kg * 2 + 0) * 64 + l) * 8);
    bf16x8 bh1 = *(const bf16x8*)(sm.f.KLs + ((kg * 2 + 1) * 64 + l) * 8);
    bf16x8 bl0 = *(const bf16x8*)(sm.f.KLs + 8192 + ((kg * 2 + 0) * 64 + l) * 8);
    bf16x8 bl1 = *(const bf16x8*)(sm.f.KLs + 8192 + ((kg * 2 + 1) * 64 + l) * 8);
    f32x4 s = {0.f, 0.f, 0.f, 0.f};
    s = MFMA16(qh0, bh0, s);
    s = MFMA16(qh0, bl0, s);
    s = MFMA16(ql0, bh0, s);
    s = MFMA16(qh1, bh1, s);
    s = MFMA16(qh1, bl1, s);
    s = MFMA16(ql1, bh1, s);
    sc[kg] = s;
  }

  // mask + single-pass softmax (C layout: row=quad*4+r, col=kg*16+lm)
  float rm[4] = {-INFINITY, -INFINITY, -INFINITY, -INFINITY};
#pragma unroll
  for (int kg = 0; kg < 8; ++kg) {
    const int col = k0 + kg * 16 + lm;
#pragma unroll
    for (int r = 0; r < 4; ++r) {
      const int row = qr0 + quad * 4 + r;
      float v = sc[kg][r] * 0.125f;
      v = (col > row || v == 0.0f) ? -INFINITY : v;
      sc[kg][r] = v;
      rm[r] = fmaxf(rm[r], v);
    }
  }
  float m_i[4], l_i[4];
#pragma unroll
  for (int r = 0; r < 4; ++r) {
    for (int off = 1; off < 16; off <<= 1) rm[r] = fmaxf(rm[r], __shfl_xor(rm[r], off, 16));
    m_i[r] = rm[r];
  }
  float rs[4] = {0.f, 0.f, 0.f, 0.f};
#pragma unroll
  for (int kg = 0; kg < 8; ++kg)
#pragma unroll
    for (int r = 0; r < 4; ++r) {
      float p = (sc[kg][r] == -INFINITY) ? 0.f : __expf(sc[kg][r] - m_i[r]);
      sc[kg][r] = p;
      rs[r] += p;
    }
#pragma unroll
  for (int r = 0; r < 4; ++r) {
    for (int off = 1; off < 16; off <<= 1) rs[r] += __shfl_xor(rs[r], off, 16);
    l_i[r] = rs[r];
  }

  // P -> Plds (C layout -> A-operand layout), per-wave private, no barrier
#pragma unroll
  for (int kg = 0; kg < 8; ++kg)
#pragma unroll
    for (int r = 0; r < 4; ++r)
      sm.f.Plds[w][quad * 4 + r][kg * 16 + lm] = f2bf(sc[kg][r]);

  // O = P V over 128 keys (V fragments already in registers)
  f32x4 o[4] = {{0.f,0.f,0.f,0.f},{0.f,0.f,0.f,0.f},{0.f,0.f,0.f,0.f},{0.f,0.f,0.f,0.f}};
#pragma unroll
  for (int kc2 = 0; kc2 < 4; ++kc2) {
    bf16x8 pf = *(const bf16x8*)&sm.f.Plds[w][lm][kc2 * 32 + quad * 8];
#pragma unroll
    for (int nt = 0; nt < 4; ++nt)
      o[nt] = MFMA16(pf, vf[kc2][nt], o[nt]);
  }

  // write partials: bf16 O (contiguous 8 KB/block) + packed (m,l)
  const int slotbase = b * 272 + slot_off(qt);
  const int slot = slotbase + c;
  short* Ob = OpartH + (size_t)slot * 4096;
#pragma unroll
  for (int nt = 0; nt < 4; ++nt)
#pragma unroll
    for (int r = 0; r < 4; ++r)
      Ob[(size_t)(w * 16 + quad * 4 + r) * AH + nt * 16 + lm] = f2bf(o[nt][r]);
  if (lm == 0) {
#pragma unroll
    for (int r = 0; r < 4; ++r)
      mlpart[(size_t)slot * 64 + w * 16 + quad * 4 + r] = make_float2(m_i[r], l_i[r]);
  }

  // ---- release + last-block merge --------------------------------------
  __syncthreads();  // all block stores complete (vmcnt drained); LDS reusable
  if (t == 0)
    s_last = (__hip_atomic_fetch_add(&CNT(b * 32 + qt), 1, __ATOMIC_RELEASE,
                                     __HIP_MEMORY_SCOPE_AGENT) == nch - 1);
  __syncthreads();
  if (!s_last) return;

  // This block saw all nch producers' releases -> their OpartH/mlpart are
  // at the coherent point; our L2 never cached those lines this dispatch
  // (fenceless-consumer protocol, R6-validated). Merge all 4 rowgroups.
  for (int rg = 0; rg < 4; ++rg) {
    __syncthreads();  // protect ldsO/wtab reuse across iterations
    const int r0 = rg * 16;
#pragma unroll
    for (int u = 0; u < 8; ++u) {
      int idx = w * 8 + u;  // 32 issues x 1 KB
      int cc = idx >> 1, half = idx & 1;
      if (cc < nch)  // wave-uniform predicate
        async16(OpartH + (size_t)(slotbase + cc) * 4096 + r0 * 64 + half * 512 + l * 8,
                sm.m.ldsO + cc * 1024 + half * 512 + l * 8);
    }

    const int row = w * 4 + (l >> 4), cw = l & 15;
    float mc = -INFINITY, lc = 0.f;
    if (cw < nch) {
      float2 ml = mlpart[(size_t)(slotbase + cw) * 64 + r0 + row];
      mc = ml.x; lc = ml.y;
    }
    float M = mc;
    for (int off = 1; off < 16; off <<= 1) M = fmaxf(M, __shfl_xor(M, off, 16));
    float wgt = (mc != -INFINITY) ? __expf(mc - M) : 0.f;
    float L = lc * wgt;
    for (int off = 1; off < 16; off <<= 1) L += __shfl_xor(L, off, 16);
    sm.m.wtab[row][cw] = wgt / L;

    __syncthreads();  // drains async staging; wtab visible

    const int row2 = t >> 4, a0 = (t & 15) * 4;
    float4 acc = make_float4(0.f, 0.f, 0.f, 0.f);
    for (int cc = 0; cc < nch; ++cc) {
      float wv = sm.m.wtab[row2][cc];
      short4 v4 = *(const short4*)(sm.m.ldsO + cc * 1024 + row2 * 64 + a0);
      acc.x += wv * bf2f(v4.x); acc.y += wv * bf2f(v4.y);
      acc.z += wv * bf2f(v4.z); acc.w += wv * bf2f(v4.w);
    }
    *(float4*)&out[((size_t)(b * 2048 + qt * 64 + r0 + row2)) * AH + a0] = acc;
  }
}

// ---------------------------------------------------------------------------
// Workspace (bytes):
//   Kpack   [0,        3145728)    4 b x 16 chunks x 48 KB
//   BpkG    [3145728,  3670016)    256 KB (+slack)
//   OpartH  [3670016,  12582912)   1088 slots x 4096 bf16
//   mlpart  [12582912, 13139968)   1088 x 64 float2
//   flags   [13139968, 13148160)   128 counters x 64B (zeroed by prep)
// ---------------------------------------------------------------------------
extern "C" void kernel_launch(void* const* d_in, const int* in_sizes, int n_in,
                              void* d_out, int out_size, void* d_ws, size_t ws_size,
                              hipStream_t stream) {
  const float* emb = (const float*)d_in[0];
  const float* Wk  = (const float*)d_in[1];
  float* out = (float*)d_out;
  char* ws = (char*)d_ws;

  short*  Kpack  = (short*)(ws);
  short*  BpkG   = (short*)(ws + 3145728);
  short*  OpartH = (short*)(ws + 3670016);
  float2* mlpart = (float2*)(ws + 12582912);
  int*    flags  = (int*)(ws + 13139968);

  prep_wk_kernel<<<dim3(32), dim3(256), 0, stream>>>(Wk, BpkG, flags);
  gemm_k_kernel<<<dim3(512), dim3(256), 0, stream>>>(emb, BpkG, Kpack);
  flash_kernel<<<dim3(16, 32, 4), dim3(256), 0, stream>>>(Kpack, OpartH, mlpart, out, flags);
}